// Round 13
// baseline (6589.267 us; speedup 1.0000x reference)
//
#include <hip/hip_runtime.h>

#define T_TOKENS 8192
#define IN_F 4096
#define OUT_F 11008

#define BM 256
#define BN 256
#define NT (IN_F / 64)   // 64 K-tiles of 64 (two k32-slices each)

typedef __attribute__((ext_vector_type(4))) int v4i;
typedef __attribute__((ext_vector_type(16))) int v16i;

__device__ __forceinline__ void load_lds16(const signed char* g, const signed char* l) {
    __builtin_amdgcn_global_load_lds(
        (const __attribute__((address_space(1))) void*)g,
        (__attribute__((address_space(3))) void*)l, 16, 0, 0);
}

// Fragment-major layout for both operands:
//   buf[blk32][k32][lane][16B], lane = hi*32 + l31, holding
//   src[blk*32 + l31][k32*32 + hi*16 .. +16]   (16 int8)
// Byte-identical to the mfma_i32_32x32x32_i8 A/B fragment per lane.

// ------------- Pass 1: fused quant (frag-major xq) + weight repack -------------
__global__ __launch_bounds__(256) void quant_repack_kernel(
        const float* __restrict__ x, signed char* __restrict__ xq,
        float* __restrict__ qscale, const int* __restrict__ w32,
        signed char* __restrict__ w8) {
    if (blockIdx.x < T_TOKENS) {
        const int row = blockIdx.x;
        const int t = threadIdx.x;
        const float4* xr = (const float4*)(x + (size_t)row * IN_F) + t * 4;
        float4 v[4];
        float am = 0.f;
#pragma unroll
        for (int i = 0; i < 4; ++i) {
            v[i] = xr[i];
            am = fmaxf(am, fmaxf(fmaxf(fabsf(v[i].x), fabsf(v[i].y)),
                                 fmaxf(fabsf(v[i].z), fabsf(v[i].w))));
        }
#pragma unroll
        for (int off = 32; off > 0; off >>= 1)
            am = fmaxf(am, __shfl_xor(am, off, 64));
        __shared__ float wmax[4];
        const int wv = t >> 6;
        if ((t & 63) == 0) wmax[wv] = am;
        __syncthreads();
        float amax = fmaxf(fmaxf(wmax[0], wmax[1]), fmaxf(wmax[2], wmax[3]));
        float qs = amax * (1.0f / 127.0f);
        if (qs < 1e-30f) qs = 1e-30f;
        const float inv = 1.0f / qs;
        if (t == 0) qscale[row] = qs;
        int q[16];
#pragma unroll
        for (int i = 0; i < 4; ++i) {
            q[i * 4 + 0] = max(-128, min(127, (int)rintf(v[i].x * inv)));
            q[i * 4 + 1] = max(-128, min(127, (int)rintf(v[i].y * inv)));
            q[i * 4 + 2] = max(-128, min(127, (int)rintf(v[i].z * inv)));
            q[i * 4 + 3] = max(-128, min(127, (int)rintf(v[i].w * inv)));
        }
        v4i p;
#pragma unroll
        for (int i = 0; i < 4; ++i)
            p[i] = (q[i * 4] & 255) | ((q[i * 4 + 1] & 255) << 8) |
                   ((q[i * 4 + 2] & 255) << 16) | ((q[i * 4 + 3] & 255) << 24);
        const int k32 = t >> 1, hi = t & 1;
        *(v4i*)(xq + (((size_t)(row >> 5)) * 128 + k32) * 1024 +
                ((hi * 32) + (row & 31)) * 16) = p;
    } else {
        const int bb = blockIdx.x - T_TOKENS;
        const int nblk = bb >> 5;
        const int kg = bb & 31;
        const int t = threadIdx.x;
        __shared__ signed char tile[32][144];
        const int rrow = t >> 3, c8 = t & 7;
        const int* src = w32 + (size_t)(nblk * 32 + rrow) * IN_F + kg * 128 + c8 * 16;
        v4i pk;
#pragma unroll
        for (int j = 0; j < 4; ++j) {
            v4i w = ((const v4i*)src)[j];
            pk[j] = (w[0] & 255) | ((w[1] & 255) << 8) |
                    ((w[2] & 255) << 16) | ((w[3] & 255) << 24);
        }
        *(v4i*)&tile[rrow][c8 * 16] = pk;
        __syncthreads();
        const int k32l = t >> 6, lane = t & 63;
        const int hi = lane >> 5, l31 = lane & 31;
        v4i o = *(const v4i*)&tile[l31][k32l * 32 + hi * 16];
        *(v4i*)(w8 + ((size_t)(nblk)*128 + kg * 4 + k32l) * 1024 + lane * 16) = o;
    }
}

// ------------- Pass 2: int8 GEMM, 4 waves x (128x128), db-2, 2 blocks/CU ----
// Block 256x256, 4 waves (2x2), per-wave 128x128 via acc[4][4] (256 AGPR).
// LDS: double-buffer 2 x 32KB = 64KB -> TWO blocks co-resident per CU
// (8 waves/CU, 2/SIMD). Cross-block TLP (unsynchronized) covers the vmcnt
// drain, lgkm read->MFMA chains, barriers, AND the partner block's
// epilogue/prologue (~24% of R7-R12's budget was this serialization).
// Geometry has the only MFMA-bound LDS ratio: 64KB reads + 32KB writes
// ~1070cyc < 1170cyc MFMA per K-tile.
// Depth-1 staging: stage t+1 right after the barrier; its drain (vmcnt(0)
// at t+1 entry) is ~1200cyc after issue > ~900cyc HBM latency.
__global__ __launch_bounds__(256, 2) void gemm_kernel(
        const signed char* __restrict__ A, const signed char* __restrict__ B,
        const float* __restrict__ qscale, const float* __restrict__ bias,
        const float* __restrict__ dqs, float* __restrict__ out) {
    __shared__ __align__(16) signed char smem_[2 * 32768];  // 64 KB
    signed char* smem = smem_;

    const int tid = threadIdx.x;
    const int wid = tid >> 6;   // 0..3
    const int lane = tid & 63;
    const int wm = wid >> 1;    // 0..1
    const int wn = wid & 1;     // 0..1
    const int l31 = lane & 31;
    const int hi = lane >> 5;

    // XCD map: XCD k owns m-tiles [4k,4k+4), sweeps n. Bijective (1376 = 8*172).
    const int b = (int)blockIdx.x;
    const int xcd = b & 7;
    const int idx = b >> 3;
    const int m0 = (xcd * 4 + (idx & 3)) * BM;
    const int n0 = (idx >> 2) * BN;

    // staging: wave w stages mblk/nblk {2w, 2w+1}: 8 gload_lds (1KB each)/tile
    const signed char* aS[2];
    const signed char* bS[2];
    int ldS[2];
#pragma unroll
    for (int j = 0; j < 2; ++j) {
        aS[j] = A + ((size_t)((m0 >> 5) + 2 * wid + j)) * 131072 + lane * 16;
        bS[j] = B + ((size_t)((n0 >> 5) + 2 * wid + j)) * 131072 + lane * 16;
        ldS[j] = (2 * wid + j) * 2048;  // wave-uniform; HW adds lane*16
    }
    // fragment read offsets (contiguous per wave -> conflict-free)
    int rdA[4], rdB[4];
#pragma unroll
    for (int im = 0; im < 4; ++im) rdA[im] = (wm * 4 + im) * 2048 + lane * 16;
#pragma unroll
    for (int in = 0; in < 4; ++in) rdB[in] = 16384 + (wn * 4 + in) * 2048 + lane * 16;

    v16i acc[4][4] = {};

    // ---- prologue: stage tile 0 into buf 0 ----
#pragma unroll
    for (int j = 0; j < 2; ++j)
#pragma unroll
        for (int ks = 0; ks < 2; ++ks) {
            load_lds16(aS[j] + ks * 1024, smem + ldS[j] + ks * 1024);
            load_lds16(bS[j] + ks * 1024, smem + 16384 + ldS[j] + ks * 1024);
        }

    // TILE(CB, SB, t): compute tile t from buf CB; stage tile t+1 into buf SB.
#define TILE(CB, SB, t) do {                                                   \
    asm volatile("s_waitcnt vmcnt(0) lgkmcnt(0)" ::: "memory");                \
    __builtin_amdgcn_sched_barrier(0);                                         \
    __builtin_amdgcn_s_barrier();                                              \
    __builtin_amdgcn_sched_barrier(0);                                         \
    if ((t) + 1 < NT) {                                                        \
        const int ko_ = ((t) + 1) * 2048;                                      \
        _Pragma("unroll")                                                      \
        for (int j = 0; j < 2; ++j)                                            \
            _Pragma("unroll")                                                  \
            for (int ks = 0; ks < 2; ++ks) {                                   \
                load_lds16(aS[j] + ko_ + ks * 1024,                            \
                           smem + (SB) * 32768 + ldS[j] + ks * 1024);          \
                load_lds16(bS[j] + ko_ + ks * 1024,                            \
                           smem + (SB) * 32768 + 16384 + ldS[j] + ks * 1024);  \
            }                                                                  \
    }                                                                          \
    __builtin_amdgcn_sched_barrier(0);                                         \
    {                                                                          \
        const signed char* rb_ = smem + (CB) * 32768;                          \
        v4i a_[4][2], b_[4][2];                                                \
        _Pragma("unroll")                                                      \
        for (int im = 0; im < 4; ++im)                                         \
            _Pragma("unroll")                                                  \
            for (int ks = 0; ks < 2; ++ks)                                     \
                a_[im][ks] = *(const v4i*)(rb_ + rdA[im] + ks * 1024);         \
        _Pragma("unroll")                                                      \
        for (int in = 0; in < 4; ++in)                                         \
            _Pragma("unroll")                                                  \
            for (int ks = 0; ks < 2; ++ks)                                     \
                b_[in][ks] = *(const v4i*)(rb_ + rdB[in] + ks * 1024);         \
        asm volatile("s_waitcnt lgkmcnt(0)" ::: "memory");                     \
        __builtin_amdgcn_sched_barrier(0);                                     \
        __builtin_amdgcn_s_setprio(1);                                         \
        _Pragma("unroll")                                                      \
        for (int ks = 0; ks < 2; ++ks)                                         \
            _Pragma("unroll")                                                  \
            for (int im = 0; im < 4; ++im)                                     \
                _Pragma("unroll")                                              \
                for (int in = 0; in < 4; ++in)                                 \
                    acc[im][in] = __builtin_amdgcn_mfma_i32_32x32x32_i8(       \
                        a_[im][ks], b_[in][ks], acc[im][in], 0, 0, 0);         \
        __builtin_amdgcn_s_setprio(0);                                         \
    }                                                                          \
} while (0)

    // main: 32 x 2 tiles; buffer parity static
    for (int t = 0; t < NT; t += 2) {
        TILE(0, 1, t);
        TILE(1, 0, t + 1);
    }
#undef TILE

    // ---- epilogue: dequant + bias ----
    const float dq = dqs[0];
#pragma unroll
    for (int im = 0; im < 4; ++im) {
        float qsv[16];
#pragma unroll
        for (int r = 0; r < 16; ++r) {
            const int trow = wm * 128 + im * 32 + (r & 3) + 8 * (r >> 2) + 4 * hi;
            qsv[r] = dq * qscale[m0 + trow];
        }
#pragma unroll
        for (int in = 0; in < 4; ++in) {
            const int col = n0 + wn * 128 + in * 32 + l31;
            const float bv = bias[col];
#pragma unroll
            for (int r = 0; r < 16; ++r) {
                const int trow = wm * 128 + im * 32 + (r & 3) + 8 * (r >> 2) + 4 * hi;
                out[(size_t)(m0 + trow) * OUT_F + col] =
                    qsv[r] * (float)acc[im][in][r] + bv;
            }
        }
    }
}

extern "C" void kernel_launch(void* const* d_in, const int* in_sizes, int n_in,
                              void* d_out, int out_size, void* d_ws, size_t ws_size,
                              hipStream_t stream) {
    const float* x    = (const float*)d_in[0];
    const int*   w32  = (const int*)d_in[1];   // int8 values stored as int32
    const float* bias = (const float*)d_in[2];
    const float* dqs  = (const float*)d_in[3];
    float* out = (float*)d_out;

    signed char* xq = (signed char*)d_ws;                                   // 33.55 MB
    float* qscale   = (float*)((char*)d_ws + (size_t)T_TOKENS * IN_F);      // 32 KB
    signed char* w8 = (signed char*)((char*)d_ws + (size_t)T_TOKENS * IN_F
                                     + (size_t)T_TOKENS * 4);               // 45.1 MB

    quant_repack_kernel<<<T_TOKENS + (OUT_F / 32) * 32, 256, 0, stream>>>(
        x, xq, qscale, w32, w8);
    dim3 g((T_TOKENS / BM) * (OUT_F / BN));  // 1376
    gemm_kernel<<<g, 256, 0, stream>>>(xq, w8, qscale, bias, dqs, out);
}

// Round 14
// 485.702 us; speedup vs baseline: 13.5665x; 13.5665x over previous
//
#include <hip/hip_runtime.h>

#define T_TOKENS 8192
#define IN_F 4096
#define OUT_F 11008

#define BM 256
#define BN 256
#define NT (IN_F / 64)   // 64 K-tiles of 64 (two k32-slices each)

typedef __attribute__((ext_vector_type(4))) int v4i;
typedef __attribute__((ext_vector_type(16))) int v16i;

__device__ __forceinline__ void load_lds16(const signed char* g, const signed char* l) {
    __builtin_amdgcn_global_load_lds(
        (const __attribute__((address_space(1))) void*)g,
        (__attribute__((address_space(3))) void*)l, 16, 0, 0);
}

// Fragment-major layout for both operands:
//   buf[blk32][k32][lane][16B], lane = hi*32 + l31, holding
//   src[blk*32 + l31][k32*32 + hi*16 .. +16]   (16 int8)
// Byte-identical to the mfma_i32_32x32x32_i8 A/B fragment per lane.

// ------------- Pass 1: fused quant (frag-major xq) + weight repack -------------
__global__ __launch_bounds__(256) void quant_repack_kernel(
        const float* __restrict__ x, signed char* __restrict__ xq,
        float* __restrict__ qscale, const int* __restrict__ w32,
        signed char* __restrict__ w8) {
    if (blockIdx.x < T_TOKENS) {
        const int row = blockIdx.x;
        const int t = threadIdx.x;
        const float4* xr = (const float4*)(x + (size_t)row * IN_F) + t * 4;
        float4 v[4];
        float am = 0.f;
#pragma unroll
        for (int i = 0; i < 4; ++i) {
            v[i] = xr[i];
            am = fmaxf(am, fmaxf(fmaxf(fabsf(v[i].x), fabsf(v[i].y)),
                                 fmaxf(fabsf(v[i].z), fabsf(v[i].w))));
        }
#pragma unroll
        for (int off = 32; off > 0; off >>= 1)
            am = fmaxf(am, __shfl_xor(am, off, 64));
        __shared__ float wmax[4];
        const int wv = t >> 6;
        if ((t & 63) == 0) wmax[wv] = am;
        __syncthreads();
        float amax = fmaxf(fmaxf(wmax[0], wmax[1]), fmaxf(wmax[2], wmax[3]));
        float qs = amax * (1.0f / 127.0f);
        if (qs < 1e-30f) qs = 1e-30f;
        const float inv = 1.0f / qs;
        if (t == 0) qscale[row] = qs;
        int q[16];
#pragma unroll
        for (int i = 0; i < 4; ++i) {
            q[i * 4 + 0] = max(-128, min(127, (int)rintf(v[i].x * inv)));
            q[i * 4 + 1] = max(-128, min(127, (int)rintf(v[i].y * inv)));
            q[i * 4 + 2] = max(-128, min(127, (int)rintf(v[i].z * inv)));
            q[i * 4 + 3] = max(-128, min(127, (int)rintf(v[i].w * inv)));
        }
        v4i p;
#pragma unroll
        for (int i = 0; i < 4; ++i)
            p[i] = (q[i * 4] & 255) | ((q[i * 4 + 1] & 255) << 8) |
                   ((q[i * 4 + 2] & 255) << 16) | ((q[i * 4 + 3] & 255) << 24);
        const int k32 = t >> 1, hi = t & 1;
        *(v4i*)(xq + (((size_t)(row >> 5)) * 128 + k32) * 1024 +
                ((hi * 32) + (row & 31)) * 16) = p;
    } else {
        const int bb = blockIdx.x - T_TOKENS;
        const int nblk = bb >> 5;
        const int kg = bb & 31;
        const int t = threadIdx.x;
        __shared__ signed char tile[32][144];
        const int rrow = t >> 3, c8 = t & 7;
        const int* src = w32 + (size_t)(nblk * 32 + rrow) * IN_F + kg * 128 + c8 * 16;
        v4i pk;
#pragma unroll
        for (int j = 0; j < 4; ++j) {
            v4i w = ((const v4i*)src)[j];
            pk[j] = (w[0] & 255) | ((w[1] & 255) << 8) |
                    ((w[2] & 255) << 16) | ((w[3] & 255) << 24);
        }
        *(v4i*)&tile[rrow][c8 * 16] = pk;
        __syncthreads();
        const int k32l = t >> 6, lane = t & 63;
        const int hi = lane >> 5, l31 = lane & 31;
        v4i o = *(const v4i*)&tile[l31][k32l * 32 + hi * 16];
        *(v4i*)(w8 + ((size_t)(nblk)*128 + kg * 4 + k32l) * 1024 + lane * 16) = o;
    }
}

// ------------- Pass 2: int8 GEMM, wave-private pipelines, ZERO barriers -----
// Block 256x256, 4 waves (2x2), per-wave 128x128 via acc[4][4] (256 AGPR,
// 1 wave/SIMD). Each wave owns a PRIVATE 32KB LDS region (2 x 16KB dbuf) and
// stages its own operand copy via global_load_lds (completion tracked by the
// wave's own vmcnt; nobody else reads the region -> NO s_barrier anywhere).
// Per tile t: vmcnt(16) [own t loads landed; t+1's 16 in flight] ->
// 16 ds_reads -> lgkmcnt(0) -> stage t+2 into the buffer just read ->
// 32 MFMA. Waves free-run and self-stagger; all convergence cost (the
// invariant ~1400cyc/tile across R7-R12's barrier/depth/pacing variants)
// is structurally removed. Staging writes 2x (64KB/tile/CU) from L2/L3.
__global__ __launch_bounds__(256, 1) void gemm_kernel(
        const signed char* __restrict__ A, const signed char* __restrict__ B,
        const float* __restrict__ qscale, const float* __restrict__ bias,
        const float* __restrict__ dqs, float* __restrict__ out) {
    __shared__ __align__(16) signed char smem_[4 * 32768];  // 128 KB
    signed char* smem = smem_;

    const int tid = threadIdx.x;
    const int wid = tid >> 6;   // 0..3
    const int lane = tid & 63;
    const int wm = wid >> 1;    // 0..1
    const int wn = wid & 1;     // 0..1
    const int l31 = lane & 31;
    const int hi = lane >> 5;

    // XCD map: XCD k owns m-tiles [4k,4k+4), sweeps n. Bijective (1376 = 8*172).
    const int b = (int)blockIdx.x;
    const int xcd = b & 7;
    const int idx = b >> 3;
    const int m0 = (xcd * 4 + (idx & 3)) * BM;
    const int n0 = (idx >> 2) * BN;

    const int wbase = wid * 32768;  // private region

    // global fragment-major sources for this wave's 4 mblk / 4 nblk
    const signed char* aSrc[4];
    const signed char* bSrc[4];
#pragma unroll
    for (int im = 0; im < 4; ++im)
        aSrc[im] = A + ((size_t)((m0 >> 5) + wm * 4 + im)) * 131072 + lane * 16;
#pragma unroll
    for (int in = 0; in < 4; ++in)
        bSrc[in] = B + ((size_t)((n0 >> 5) + wn * 4 + in)) * 131072 + lane * 16;

    v16i acc[4][4] = {};

    // STAGE(BUF, t): 16 gload_lds of tile t into private buffer BUF.
#define STAGE(BUF, t) do {                                                     \
    const int ko_ = (t) * 2048;                                                \
    _Pragma("unroll")                                                          \
    for (int im = 0; im < 4; ++im)                                             \
        _Pragma("unroll")                                                      \
        for (int ks = 0; ks < 2; ++ks)                                         \
            load_lds16(aSrc[im] + ko_ + ks * 1024,                             \
                       smem + wbase + (BUF) * 16384 + im * 2048 + ks * 1024);  \
    _Pragma("unroll")                                                          \
    for (int in = 0; in < 4; ++in)                                             \
        _Pragma("unroll")                                                      \
        for (int ks = 0; ks < 2; ++ks)                                         \
            load_lds16(bSrc[in] + ko_ + ks * 1024,                             \
                       smem + wbase + (BUF) * 16384 + 8192 + in * 2048 +       \
                           ks * 1024);                                         \
} while (0)

    // ---- prologue: stage tiles 0,1 into private bufs 0,1 ----
    STAGE(0, 0);
    STAGE(1, 1);

    // TILE(CB, t, VMC, DOSTAGE): wave-private pipeline step, no barriers.
#define TILE(CB, t, VMC, DOSTAGE) do {                                         \
    asm volatile("s_waitcnt vmcnt(" #VMC ")" ::: "memory");                    \
    __builtin_amdgcn_sched_barrier(0);                                         \
    {                                                                          \
        const signed char* rb_ = smem + wbase + (CB) * 16384;                  \
        v4i a_[4][2], b_[4][2];                                                \
        _Pragma("unroll")                                                      \
        for (int im = 0; im < 4; ++im)                                         \
            _Pragma("unroll")                                                  \
            for (int ks = 0; ks < 2; ++ks)                                     \
                a_[im][ks] = *(const v4i*)(rb_ + im * 2048 + ks * 1024 +       \
                                           lane * 16);                         \
        _Pragma("unroll")                                                      \
        for (int in = 0; in < 4; ++in)                                         \
            _Pragma("unroll")                                                  \
            for (int ks = 0; ks < 2; ++ks)                                     \
                b_[in][ks] = *(const v4i*)(rb_ + 8192 + in * 2048 +            \
                                           ks * 1024 + lane * 16);             \
        asm volatile("s_waitcnt lgkmcnt(0)" ::: "memory");                     \
        __builtin_amdgcn_sched_barrier(0);                                     \
        if (DOSTAGE) STAGE(CB, (t) + 2);                                       \
        __builtin_amdgcn_sched_barrier(0);                                     \
        _Pragma("unroll")                                                      \
        for (int ks = 0; ks < 2; ++ks)                                         \
            _Pragma("unroll")                                                  \
            for (int im = 0; im < 4; ++im)                                     \
                _Pragma("unroll")                                              \
                for (int in = 0; in < 4; ++in)                                 \
                    acc[im][in] = __builtin_amdgcn_mfma_i32_32x32x32_i8(       \
                        a_[im][ks], b_[in][ks], acc[im][in], 0, 0, 0);         \
    }                                                                          \
} while (0)

    // main: tiles 0..61 stage t+2; 62 no stage; 63 final drain
    for (int t = 0; t < 60; t += 2) {
        TILE(0, t, 16, 1);
        TILE(1, t + 1, 16, 1);
    }
    TILE(0, 60, 16, 1);
    TILE(1, 61, 16, 1);
    TILE(0, 62, 16, 0);
    TILE(1, 63, 0, 0);
#undef TILE
#undef STAGE

    // ---- epilogue: dequant + bias ----
    const float dq = dqs[0];
#pragma unroll
    for (int im = 0; im < 4; ++im) {
        float qsv[16];
#pragma unroll
        for (int r = 0; r < 16; ++r) {
            const int trow = wm * 128 + im * 32 + (r & 3) + 8 * (r >> 2) + 4 * hi;
            qsv[r] = dq * qscale[m0 + trow];
        }
#pragma unroll
        for (int in = 0; in < 4; ++in) {
            const int col = n0 + wn * 128 + in * 32 + l31;
            const float bv = bias[col];
#pragma unroll
            for (int r = 0; r < 16; ++r) {
                const int trow = wm * 128 + im * 32 + (r & 3) + 8 * (r >> 2) + 4 * hi;
                out[(size_t)(m0 + trow) * OUT_F + col] =
                    qsv[r] * (float)acc[im][in][r] + bv;
            }
        }
    }
}

extern "C" void kernel_launch(void* const* d_in, const int* in_sizes, int n_in,
                              void* d_out, int out_size, void* d_ws, size_t ws_size,
                              hipStream_t stream) {
    const float* x    = (const float*)d_in[0];
    const int*   w32  = (const int*)d_in[1];   // int8 values stored as int32
    const float* bias = (const float*)d_in[2];
    const float* dqs  = (const float*)d_in[3];
    float* out = (float*)d_out;

    signed char* xq = (signed char*)d_ws;                                   // 33.55 MB
    float* qscale   = (float*)((char*)d_ws + (size_t)T_TOKENS * IN_F);      // 32 KB
    signed char* w8 = (signed char*)((char*)d_ws + (size_t)T_TOKENS * IN_F
                                     + (size_t)T_TOKENS * 4);               // 45.1 MB

    quant_repack_kernel<<<T_TOKENS + (OUT_F / 32) * 32, 256, 0, stream>>>(
        x, xq, qscale, w32, w8);
    dim3 g((T_TOKENS / BM) * (OUT_F / BN));  // 1376
    gemm_kernel<<<g, 256, 0, stream>>>(xq, w8, qscale, bias, dqs, out);
}

// Round 15
// 466.823 us; speedup vs baseline: 14.1151x; 1.0404x over previous
//
#include <hip/hip_runtime.h>

#define T_TOKENS 8192
#define IN_F 4096
#define OUT_F 11008

#define BM 256
#define BN 128
#define NT (IN_F / 64)   // 64 K-tiles of 64 (two k32-slices each)

typedef __attribute__((ext_vector_type(4))) int v4i;
typedef __attribute__((ext_vector_type(16))) int v16i;

__device__ __forceinline__ void load_lds16(const signed char* g, const signed char* l) {
    __builtin_amdgcn_global_load_lds(
        (const __attribute__((address_space(1))) void*)g,
        (__attribute__((address_space(3))) void*)l, 16, 0, 0);
}

// Fragment-major layout for both operands:
//   buf[blk32][k32][lane][16B], lane = hi*32 + l31, holding
//   src[blk*32 + l31][k32*32 + hi*16 .. +16]   (16 int8)
// Byte-identical to the mfma_i32_32x32x32_i8 A/B fragment per lane.

// ------------- Pass 1: fused quant (frag-major xq) + weight repack -------------
__global__ __launch_bounds__(256) void quant_repack_kernel(
        const float* __restrict__ x, signed char* __restrict__ xq,
        float* __restrict__ qscale, const int* __restrict__ w32,
        signed char* __restrict__ w8) {
    if (blockIdx.x < T_TOKENS) {
        const int row = blockIdx.x;
        const int t = threadIdx.x;
        const float4* xr = (const float4*)(x + (size_t)row * IN_F) + t * 4;
        float4 v[4];
        float am = 0.f;
#pragma unroll
        for (int i = 0; i < 4; ++i) {
            v[i] = xr[i];
            am = fmaxf(am, fmaxf(fmaxf(fabsf(v[i].x), fabsf(v[i].y)),
                                 fmaxf(fabsf(v[i].z), fabsf(v[i].w))));
        }
#pragma unroll
        for (int off = 32; off > 0; off >>= 1)
            am = fmaxf(am, __shfl_xor(am, off, 64));
        __shared__ float wmax[4];
        const int wv = t >> 6;
        if ((t & 63) == 0) wmax[wv] = am;
        __syncthreads();
        float amax = fmaxf(fmaxf(wmax[0], wmax[1]), fmaxf(wmax[2], wmax[3]));
        float qs = amax * (1.0f / 127.0f);
        if (qs < 1e-30f) qs = 1e-30f;
        const float inv = 1.0f / qs;
        if (t == 0) qscale[row] = qs;
        int q[16];
#pragma unroll
        for (int i = 0; i < 4; ++i) {
            q[i * 4 + 0] = max(-128, min(127, (int)rintf(v[i].x * inv)));
            q[i * 4 + 1] = max(-128, min(127, (int)rintf(v[i].y * inv)));
            q[i * 4 + 2] = max(-128, min(127, (int)rintf(v[i].z * inv)));
            q[i * 4 + 3] = max(-128, min(127, (int)rintf(v[i].w * inv)));
        }
        v4i p;
#pragma unroll
        for (int i = 0; i < 4; ++i)
            p[i] = (q[i * 4] & 255) | ((q[i * 4 + 1] & 255) << 8) |
                   ((q[i * 4 + 2] & 255) << 16) | ((q[i * 4 + 3] & 255) << 24);
        const int k32 = t >> 1, hi = t & 1;
        *(v4i*)(xq + (((size_t)(row >> 5)) * 128 + k32) * 1024 +
                ((hi * 32) + (row & 31)) * 16) = p;
    } else {
        const int bb = blockIdx.x - T_TOKENS;
        const int nblk = bb >> 5;
        const int kg = bb & 31;
        const int t = threadIdx.x;
        __shared__ signed char tile[32][144];
        const int rrow = t >> 3, c8 = t & 7;
        const int* src = w32 + (size_t)(nblk * 32 + rrow) * IN_F + kg * 128 + c8 * 16;
        v4i pk;
#pragma unroll
        for (int j = 0; j < 4; ++j) {
            v4i w = ((const v4i*)src)[j];
            pk[j] = (w[0] & 255) | ((w[1] & 255) << 8) |
                    ((w[2] & 255) << 16) | ((w[3] & 255) << 24);
        }
        *(v4i*)&tile[rrow][c8 * 16] = pk;
        __syncthreads();
        const int k32l = t >> 6, lane = t & 63;
        const int hi = lane >> 5, l31 = lane & 31;
        v4i o = *(const v4i*)&tile[l31][k32l * 32 + hi * 16];
        *(v4i*)(w8 + ((size_t)(nblk)*128 + kg * 4 + k32l) * 1024 + lane * 16) = o;
    }
}

// ------------- Pass 2: int8 GEMM, 256x128 block, TWO blocks/CU ---------------
// 4 waves (2Mx2N), per-wave 128x64 via acc[4][2] (128 AGPR, ~210 regs total,
// fits launch_bounds(256,2) WITHOUT spill — R13's bug was acc[4][4]=256).
// LDS: ring-3 x 24KB = 72KB/block -> 2 blocks/CU -> every SIMD carries 2
// waves from DIFFERENT (unsynchronized) blocks: one block's MFMA covers the
// other's staging/waits/epilogue (m114/m97 mechanism — the one axis the
// R7-R14 null matrix never exercised; all those kept co-SIMD waves in one
// dependency domain and measured period = MFMA + overhead, sum not max).
// Loop: 1 barrier/tile, counted vmcnt(6) (never 0 until drain), frag-major
// conflict-free b128 reads, stage-after-barrier (ring-3 race closed by the
// lgkm-consumed-before-barrier argument + tile-top lgkmcnt(0)).
__global__ __launch_bounds__(256, 2) void gemm_kernel(
        const signed char* __restrict__ A, const signed char* __restrict__ B,
        const float* __restrict__ qscale, const float* __restrict__ bias,
        const float* __restrict__ dqs, float* __restrict__ out) {
    __shared__ __align__(16) signed char smem_[3 * 24576];  // 72 KB
    signed char* smem = smem_;

    const int tid = threadIdx.x;
    const int wid = tid >> 6;   // 0..3
    const int lane = tid & 63;
    const int wm = wid >> 1;    // 0..1
    const int wn = wid & 1;     // 0..1
    const int l31 = lane & 31;
    const int hi = lane >> 5;

    // XCD map: XCD k owns m-tiles [4k,4k+4), sweeps n. Bijective (2752 = 8*344).
    const int b = (int)blockIdx.x;
    const int xcd = b & 7;
    const int idx = b >> 3;                  // 0..343
    const int m0 = (xcd * 4 + (idx & 3)) * BM;
    const int n0 = (idx >> 2) * BN;          // 0..85

    // staging per wave per tile: A mblk {2w,2w+1} (4 x 1KB) + B nblk w (2 x 1KB)
    const signed char* aS[4];
    const signed char* bS[2];
    int ldsA[4], ldsB[2];
#pragma unroll
    for (int c = 0; c < 4; ++c) {
        const int mb = 2 * wid + (c >> 1);
        aS[c] = A + ((size_t)((m0 >> 5) + mb)) * 131072 + (c & 1) * 1024 + lane * 16;
        ldsA[c] = mb * 2048 + (c & 1) * 1024;   // wave-uniform; HW adds lane*16
    }
#pragma unroll
    for (int c = 0; c < 2; ++c) {
        bS[c] = B + ((size_t)((n0 >> 5) + wid)) * 131072 + c * 1024 + lane * 16;
        ldsB[c] = 16384 + wid * 2048 + c * 1024;
    }
    // fragment read offsets (contiguous per wave -> conflict-free)
    int rdA[4][2], rdB[2][2];
#pragma unroll
    for (int im = 0; im < 4; ++im)
#pragma unroll
        for (int ks = 0; ks < 2; ++ks)
            rdA[im][ks] = (wm * 4 + im) * 2048 + ks * 1024 + lane * 16;
#pragma unroll
    for (int in = 0; in < 2; ++in)
#pragma unroll
        for (int ks = 0; ks < 2; ++ks)
            rdB[in][ks] = 16384 + (wn * 2 + in) * 2048 + ks * 1024 + lane * 16;

    v16i acc[4][2] = {};

    // ---- prologue: stage tiles 0,1 into bufs 0,1 (6 gloads/wave each) ----
#pragma unroll
    for (int tt = 0; tt < 2; ++tt) {
#pragma unroll
        for (int c = 0; c < 4; ++c)
            load_lds16(aS[c] + tt * 2048, smem + tt * 24576 + ldsA[c]);
#pragma unroll
        for (int c = 0; c < 2; ++c)
            load_lds16(bS[c] + tt * 2048, smem + tt * 24576 + ldsB[c]);
    }

    // TILE(CB, SB, t, VMC, DOSTAGE): 1 barrier, counted vmcnt, same-tile reads.
#define TILE(CB, SB, t, VMC, DOSTAGE) do {                                     \
    asm volatile("s_waitcnt vmcnt(" #VMC ") lgkmcnt(0)" ::: "memory");         \
    __builtin_amdgcn_sched_barrier(0);                                         \
    __builtin_amdgcn_s_barrier();                                              \
    __builtin_amdgcn_sched_barrier(0);                                         \
    if (DOSTAGE) {                                                             \
        const int ko_ = ((t) + 2) * 2048;                                      \
        _Pragma("unroll")                                                      \
        for (int c = 0; c < 4; ++c)                                            \
            load_lds16(aS[c] + ko_, smem + (SB) * 24576 + ldsA[c]);            \
        _Pragma("unroll")                                                      \
        for (int c = 0; c < 2; ++c)                                            \
            load_lds16(bS[c] + ko_, smem + (SB) * 24576 + ldsB[c]);            \
    }                                                                          \
    __builtin_amdgcn_sched_barrier(0);                                         \
    {                                                                          \
        const signed char* rb_ = smem + (CB) * 24576;                          \
        v4i a_[4][2], bf_[2][2];                                               \
        _Pragma("unroll")                                                      \
        for (int im = 0; im < 4; ++im)                                         \
            _Pragma("unroll")                                                  \
            for (int ks = 0; ks < 2; ++ks)                                     \
                a_[im][ks] = *(const v4i*)(rb_ + rdA[im][ks]);                 \
        _Pragma("unroll")                                                      \
        for (int in = 0; in < 2; ++in)                                         \
            _Pragma("unroll")                                                  \
            for (int ks = 0; ks < 2; ++ks)                                     \
                bf_[in][ks] = *(const v4i*)(rb_ + rdB[in][ks]);                \
        __builtin_amdgcn_s_setprio(1);                                         \
        _Pragma("unroll")                                                      \
        for (int ks = 0; ks < 2; ++ks)                                         \
            _Pragma("unroll")                                                  \
            for (int im = 0; im < 4; ++im)                                     \
                _Pragma("unroll")                                              \
                for (int in = 0; in < 2; ++in)                                 \
                    acc[im][in] = __builtin_amdgcn_mfma_i32_32x32x32_i8(       \
                        a_[im][ks], bf_[in][ks], acc[im][in], 0, 0, 0);        \
        __builtin_amdgcn_s_setprio(0);                                         \
    }                                                                          \
} while (0)

    // main: 20 x 3 tiles (0..59, all stage t+2 <= 61), buf = t % 3 static
    for (int t = 0; t < 60; t += 3) {
        TILE(0, 2, t,     6, 1);
        TILE(1, 0, t + 1, 6, 1);
        TILE(2, 1, t + 2, 6, 1);
    }
    // tail: 60 (stage 62), 61 (stage 63), 62, 63 (drain)
    TILE(0, 2, 60, 6, 1);
    TILE(1, 0, 61, 6, 1);
    TILE(2, 0, 62, 6, 0);
    TILE(0, 0, 63, 0, 0);
#undef TILE

    // ---- epilogue: dequant + bias ----
    const float dq = dqs[0];
#pragma unroll
    for (int im = 0; im < 4; ++im) {
        float qsv[16];
#pragma unroll
        for (int r = 0; r < 16; ++r) {
            const int trow = wm * 128 + im * 32 + (r & 3) + 8 * (r >> 2) + 4 * hi;
            qsv[r] = dq * qscale[m0 + trow];
        }
#pragma unroll
        for (int in = 0; in < 2; ++in) {
            const int col = n0 + wn * 64 + in * 32 + l31;
            const float bv = bias[col];
#pragma unroll
            for (int r = 0; r < 16; ++r) {
                const int trow = wm * 128 + im * 32 + (r & 3) + 8 * (r >> 2) + 4 * hi;
                out[(size_t)(m0 + trow) * OUT_F + col] =
                    qsv[r] * (float)acc[im][in][r] + bv;
            }
        }
    }
}

extern "C" void kernel_launch(void* const* d_in, const int* in_sizes, int n_in,
                              void* d_out, int out_size, void* d_ws, size_t ws_size,
                              hipStream_t stream) {
    const float* x    = (const float*)d_in[0];
    const int*   w32  = (const int*)d_in[1];   // int8 values stored as int32
    const float* bias = (const float*)d_in[2];
    const float* dqs  = (const float*)d_in[3];
    float* out = (float*)d_out;

    signed char* xq = (signed char*)d_ws;                                   // 33.55 MB
    float* qscale   = (float*)((char*)d_ws + (size_t)T_TOKENS * IN_F);      // 32 KB
    signed char* w8 = (signed char*)((char*)d_ws + (size_t)T_TOKENS * IN_F
                                     + (size_t)T_TOKENS * 4);               // 45.1 MB

    quant_repack_kernel<<<T_TOKENS + (OUT_F / 32) * 32, 256, 0, stream>>>(
        x, xq, qscale, w32, w8);
    dim3 g((T_TOKENS / BM) * (OUT_F / BN));  // 32 * 86 = 2752
    gemm_kernel<<<g, 256, 0, stream>>>(xq, w8, qscale, bias, dqs, out);
}